// Round 9
// baseline (108.517 us; speedup 1.0000x reference)
//
#include <hip/hip_runtime.h>

static constexpr int IH = 480;
static constexpr int IW = 640;
static constexpr int IHW = IH * IW;
static constexpr int PXPB  = 4096;                 // pixels per block chunk
static constexpr int ITERS = PXPB / (256 * 4);     // 4 iterations, 4 px/thread/iter

typedef float f32x4  __attribute__((ext_vector_type(4)));
typedef float f32x4u __attribute__((ext_vector_type(4), aligned(4)));  // unaligned-capable

// 8 (axis, dir) combos in reference order: ud d1/d2, lr d1/d2, lu d1/d2, ld d1/d2
__device__ __constant__ const int c_oy[8] = { -1, +1,  0,  0, -1, +1, -1, +1 };
__device__ __constant__ const int c_ox[8] = {  0,  0, -1, +1, -1, +1, +1, -1 };

__global__ __launch_bounds__(256) void prop_kernel(
    const float* __restrict__ depth,
    const float* __restrict__ normal,
    const float* __restrict__ rgb,
    const float* __restrict__ conf,
    const float* __restrict__ Kinv,
    float* __restrict__ out)
{
    const int c  = blockIdx.y;          // combo 0..23
    const int bi = blockIdx.z;          // batch
    const int oi = c >> 3;
    const int k  = c & 7;
    const int o  = 2 * oi + 1;          // 1, 3, 5
    const int oy = c_oy[k] * o;
    const int ox = c_ox[k] * o;

    const float* dp  = depth  + (size_t)bi * IHW;
    const float* cfp = conf   + (size_t)bi * IHW;
    const float* nr  = normal + (size_t)bi * 3 * IHW;
    const float* rg  = rgb    + (size_t)bi * 3 * IHW;

    const float* Ki = Kinv + bi * 9;
    const float k00 = Ki[0], k01 = Ki[1], k02 = Ki[2];
    const float k10 = Ki[3], k11 = Ki[4], k12 = Ki[5];
    const float k20 = Ki[6], k21 = Ki[7], k22 = Ki[8];
    const float fox = (float)ox, foy = (float)oy;
    const float e0 = fox * k00 + foy * k01;   // K_inv * (ox, oy, 0)
    const float e1 = fox * k10 + foy * k11;
    const float e2 = fox * k20 + foy * k21;

    float* outc = out + (((size_t)bi * 24 + c) * 5) * IHW;

#pragma unroll
    for (int it = 0; it < ITERS; ++it) {
        const int p0 = blockIdx.x * PXPB + it * 1024 + threadIdx.x * 4;
        const int y  = p0 / IW;
        const int x0 = p0 - y * IW;
        const int sy = y + oy;
        const bool rowin   = (sy >= 0) & (sy < IH);
        const bool fullcol = (x0 + ox >= 0) & (x0 + 3 + ox < IW);

        f32x4 vd, vc, v0, v1, v2;

        if (rowin & fullcol) {
            const int spi = sy * IW + x0 + ox;
            const f32x4 ds = *reinterpret_cast<const f32x4u*>(dp  + spi);
            const f32x4 n0 = *reinterpret_cast<const f32x4u*>(nr  + spi);
            const f32x4 n1 = *reinterpret_cast<const f32x4u*>(nr  + IHW + spi);
            const f32x4 n2 = *reinterpret_cast<const f32x4u*>(nr  + 2 * IHW + spi);
            vc = *reinterpret_cast<const f32x4u*>(cfp + spi);
            v0 = *reinterpret_cast<const f32x4u*>(rg  + spi);
            v1 = *reinterpret_cast<const f32x4u*>(rg  + IHW + spi);
            v2 = *reinterpret_cast<const f32x4u*>(rg  + 2 * IHW + spi);
            const float fy = (float)y;
#pragma unroll
            for (int i = 0; i < 4; ++i) {
                const float fx = (float)(x0 + i);
                const float r0 = k00 * fx + k01 * fy + k02;   // ray at dest px
                const float r1 = k10 * fx + k11 * fy + k12;
                const float r2 = k20 * fx + k21 * fy + k22;
                const float den = n0[i] * r0 + n1[i] * r1 + n2[i] * r2;
                const float t   = den + n0[i] * e0 + n1[i] * e1 + n2[i] * e2;
                const float w   = ds[i] * t * __builtin_amdgcn_rcpf(den + 1e-18f);
                vd[i] = fminf(fmaxf(w, 0.01f), 10.0f);
            }
        } else if (rowin) {
            const float fy = (float)y;
#pragma unroll
            for (int i = 0; i < 4; ++i) {
                const int sx = x0 + i + ox;
                if (sx >= 0 && sx < IW) {
                    const int sp = sy * IW + sx;
                    const float n0 = nr[sp];
                    const float n1 = nr[IHW + sp];
                    const float n2 = nr[2 * IHW + sp];
                    const float fx = (float)(x0 + i);
                    const float r0 = k00 * fx + k01 * fy + k02;
                    const float r1 = k10 * fx + k11 * fy + k12;
                    const float r2 = k20 * fx + k21 * fy + k22;
                    const float den = n0 * r0 + n1 * r1 + n2 * r2;
                    const float t   = den + n0 * e0 + n1 * e1 + n2 * e2;
                    const float w   = dp[sp] * t * __builtin_amdgcn_rcpf(den + 1e-18f);
                    vd[i] = fminf(fmaxf(w, 0.01f), 10.0f);
                    vc[i] = cfp[sp];
                    v0[i] = rg[sp];
                    v1[i] = rg[IHW + sp];
                    v2[i] = rg[2 * IHW + sp];
                } else {
                    vd[i] = dp[p0 + i];   // boundary pass-through
                    vc[i] = 0.0f; v0[i] = 0.0f; v1[i] = 0.0f; v2[i] = 0.0f;
                }
            }
        } else {
#pragma unroll
            for (int i = 0; i < 4; ++i) {
                const int sx = x0 + i + ox;
                // ld-d2 quirk: bottom boundary passes depth[y, x-o] through
                if (k == 7 && sy >= IH && sx >= 0) vd[i] = dp[y * IW + sx];
                else                               vd[i] = dp[p0 + i];
            }
            vc = (f32x4)0.0f; v0 = (f32x4)0.0f; v1 = (f32x4)0.0f; v2 = (f32x4)0.0f;
        }

        *reinterpret_cast<f32x4*>(outc + p0)           = vd;
        *reinterpret_cast<f32x4*>(outc + IHW + p0)     = vc;
        *reinterpret_cast<f32x4*>(outc + 2 * IHW + p0) = v0;
        *reinterpret_cast<f32x4*>(outc + 3 * IHW + p0) = v1;
        *reinterpret_cast<f32x4*>(outc + 4 * IHW + p0) = v2;
    }
}

extern "C" void kernel_launch(void* const* d_in, const int* in_sizes, int n_in,
                              void* d_out, int out_size, void* d_ws, size_t ws_size,
                              hipStream_t stream) {
    const float* depth  = (const float*)d_in[0];
    const float* normal = (const float*)d_in[1];
    const float* rgb    = (const float*)d_in[2];
    const float* conf   = (const float*)d_in[3];
    const float* Kinv   = (const float*)d_in[4];
    float* out = (float*)d_out;

    const int B = in_sizes[0] / IHW;
    dim3 grid(IHW / PXPB, 24, B);   // 75 x-chunks, one combo per y-block
    dim3 block(256, 1, 1);

    hipLaunchKernelGGL(prop_kernel, grid, block, 0, stream,
                       depth, normal, rgb, conf, Kinv, out);
}

// Round 10
// 98.836 us; speedup vs baseline: 1.0979x; 1.0979x over previous
//
#include <hip/hip_runtime.h>

static constexpr int IH = 480;
static constexpr int IW = 640;
static constexpr int IHW = IH * IW;
static constexpr int PPT   = 16;            // pixels per thread
static constexpr int CHUNK = 256 * PPT;     // 4096 px per block
static constexpr int NCHUNK = IHW / CHUNK;  // 75

// 8 (axis, dir) combos in reference order: ud d1/d2, lr d1/d2, lu d1/d2, ld d1/d2
__device__ __constant__ const int c_oy[8] = { -1, +1,  0,  0, -1, +1, -1, +1 };
__device__ __constant__ const int c_ox[8] = {  0,  0, -1, +1, -1, +1, +1, -1 };

__global__ __launch_bounds__(256) void prop_kernel(
    const float* __restrict__ depth,
    const float* __restrict__ normal,
    const float* __restrict__ rgb,
    const float* __restrict__ conf,
    const float* __restrict__ Kinv,
    float* __restrict__ out)
{
    const int q  = blockIdx.y;          // output plane 0..119
    const int bi = blockIdx.z;          // batch
    const int c  = q / 5;               // combo 0..23
    const int ch = q - c * 5;           // channel: 0=depth, 1=conf, 2..4=rgb
    const int oi = c >> 3;
    const int k  = c & 7;
    const int o  = 2 * oi + 1;          // 1, 3, 5
    const int oy = c_oy[k] * o;
    const int ox = c_ox[k] * o;
    const int d  = oy * IW + ox;        // flat source offset

    const int base = blockIdx.x * CHUNK + threadIdx.x;
    float* ob = out + (((size_t)bi * 24 + c) * 5 + ch) * IHW;

    if (ch != 0) {
        // pure shifted-memcpy plane: one scalar load + one scalar NT store per px
        const float* spl = (ch == 1) ? (conf + (size_t)bi * IHW)
                                     : (rgb + ((size_t)bi * 3 + (ch - 2)) * IHW);
#pragma unroll
        for (int j = 0; j < PPT; ++j) {
            const int p  = base + j * 256;
            const int y  = p / IW;
            const int x  = p - y * IW;
            const int sy = y + oy;
            const int sx = x + ox;
            float v = 0.0f;
            if (sy >= 0 && sy < IH && sx >= 0 && sx < IW) v = spl[p + d];
            __builtin_nontemporal_store(v, ob + p);
        }
        return;
    }

    // depth plane
    const float* dp = depth  + (size_t)bi * IHW;
    const float* nr = normal + (size_t)bi * 3 * IHW;
    const float* Ki = Kinv + bi * 9;
    const float k00 = Ki[0], k01 = Ki[1], k02 = Ki[2];
    const float k10 = Ki[3], k11 = Ki[4], k12 = Ki[5];
    const float k20 = Ki[6], k21 = Ki[7], k22 = Ki[8];
    const float fox = (float)ox, foy = (float)oy;
    const float e0 = fox * k00 + foy * k01;   // K_inv * (ox, oy, 0)
    const float e1 = fox * k10 + foy * k11;
    const float e2 = fox * k20 + foy * k21;

#pragma unroll
    for (int j = 0; j < PPT; ++j) {
        const int p  = base + j * 256;
        const int y  = p / IW;
        const int x  = p - y * IW;
        const int sy = y + oy;
        const int sx = x + ox;
        float v;
        if (sy >= 0 && sy < IH && sx >= 0 && sx < IW) {
            const int sp = p + d;
            const float n0 = nr[sp];
            const float n1 = nr[IHW + sp];
            const float n2 = nr[2 * IHW + sp];
            const float ds = dp[sp];
            const float fx = (float)x, fy = (float)y;
            const float r0 = k00 * fx + k01 * fy + k02;   // ray at dest pixel
            const float r1 = k10 * fx + k11 * fy + k12;
            const float r2 = k20 * fx + k21 * fy + k22;
            const float den = n0 * r0 + n1 * r1 + n2 * r2;
            const float t   = den + n0 * e0 + n1 * e1 + n2 * e2;
            const float w   = ds * t * __builtin_amdgcn_rcpf(den + 1e-18f);
            v = fminf(fmaxf(w, 0.01f), 10.0f);
        } else if (k == 7 && sy >= IH && sx >= 0) {
            // ld-d2 quirk: bottom boundary passes depth[y, x-o] through
            v = dp[p + ox];
        } else {
            v = dp[p];
        }
        __builtin_nontemporal_store(v, ob + p);
    }
}

extern "C" void kernel_launch(void* const* d_in, const int* in_sizes, int n_in,
                              void* d_out, int out_size, void* d_ws, size_t ws_size,
                              hipStream_t stream) {
    const float* depth  = (const float*)d_in[0];
    const float* normal = (const float*)d_in[1];
    const float* rgb    = (const float*)d_in[2];
    const float* conf   = (const float*)d_in[3];
    const float* Kinv   = (const float*)d_in[4];
    float* out = (float*)d_out;

    const int B = in_sizes[0] / IHW;
    dim3 grid(NCHUNK, 120, B);   // 75 chunks, one output plane per y-block
    dim3 block(256, 1, 1);

    hipLaunchKernelGGL(prop_kernel, grid, block, 0, stream,
                       depth, normal, rgb, conf, Kinv, out);
}

// Round 11
// 83.516 us; speedup vs baseline: 1.2994x; 1.1834x over previous
//
#include <hip/hip_runtime.h>

static constexpr int IH = 480;
static constexpr int IW = 640;
static constexpr int IHW = IH * IW;

typedef float f32x4 __attribute__((ext_vector_type(4)));

// 8 (axis, dir) combos in reference order: ud d1/d2, lr d1/d2, lu d1/d2, ld d1/d2
__device__ __constant__ const int c_oy[8] = { -1, +1,  0,  0, -1, +1, -1, +1 };
__device__ __constant__ const int c_ox[8] = {  0,  0, -1, +1, -1, +1, +1, -1 };

__global__ __launch_bounds__(256, 4) void prop_kernel(
    const float* __restrict__ depth,
    const float* __restrict__ normal,
    const float* __restrict__ rgb,
    const float* __restrict__ conf,
    const float* __restrict__ Kinv,
    float* __restrict__ out)
{
    const int c  = blockIdx.y;          // combo 0..23
    const int bi = blockIdx.z;          // batch
    const int oi = c >> 3;
    const int k  = c & 7;
    const int o  = 2 * oi + 1;          // 1, 3, 5
    const int oy = c_oy[k] * o;
    const int ox = c_ox[k] * o;
    const int d  = oy * IW + ox;        // flat source offset (IW%4==0 -> d%4 == ox%4)
    const int r  = ((ox % 4) + 4) & 3;  // sub-dword misalignment, block-uniform

    const int p0 = (blockIdx.x * 256 + threadIdx.x) * 4;  // 4 px, same row, 16B aligned
    const int y  = p0 / IW;
    const int x0 = p0 - y * IW;
    const int sy = y + oy;
    const int ax = x0 + ox - r;         // aligned source x of first load

    const float* dp  = depth  + (size_t)bi * IHW;
    const float* cfp = conf   + (size_t)bi * IHW;
    const float* nr  = normal + (size_t)bi * 3 * IHW;
    const float* rg  = rgb    + (size_t)bi * 3 * IHW;

    const float* Ki = Kinv + bi * 9;
    const float k00 = Ki[0], k01 = Ki[1], k02 = Ki[2];
    const float k10 = Ki[3], k11 = Ki[4], k12 = Ki[5];
    const float k20 = Ki[6], k21 = Ki[7], k22 = Ki[8];
    const float fox = (float)ox, foy = (float)oy;
    const float e0 = fox * k00 + foy * k01;   // K_inv * (ox, oy, 0)
    const float e1 = fox * k10 + foy * k11;
    const float e2 = fox * k20 + foy * k21;

    f32x4 vd, vc, v0, v1, v2;

    const bool fast = (sy >= 0) & (sy < IH) & (ax >= 0) & (ax + (r ? 8 : 4) <= IW);
    if (fast) {
        const int ap = p0 + d - r;      // 16B-aligned flat source index
        auto LD4 = [&](const float* pl) -> f32x4 {
            const f32x4 a = *reinterpret_cast<const f32x4*>(pl + ap);
            if (r == 0) return a;
            const f32x4 b = *reinterpret_cast<const f32x4*>(pl + ap + 4);
            switch (r) {
                case 1:  return __builtin_shufflevector(a, b, 1, 2, 3, 4);
                case 2:  return __builtin_shufflevector(a, b, 2, 3, 4, 5);
                default: return __builtin_shufflevector(a, b, 3, 4, 5, 6);
            }
        };
        const f32x4 ds = LD4(dp);
        const f32x4 n0 = LD4(nr);
        const f32x4 n1 = LD4(nr + IHW);
        const f32x4 n2 = LD4(nr + 2 * IHW);
        vc = LD4(cfp);
        v0 = LD4(rg);
        v1 = LD4(rg + IHW);
        v2 = LD4(rg + 2 * IHW);

        const float fy = (float)y;
#pragma unroll
        for (int i = 0; i < 4; ++i) {
            const float fx = (float)(x0 + i);
            const float r0 = k00 * fx + k01 * fy + k02;   // ray at dest pixel
            const float r1 = k10 * fx + k11 * fy + k12;
            const float r2 = k20 * fx + k21 * fy + k22;
            const float den = n0[i] * r0 + n1[i] * r1 + n2[i] * r2;
            const float t   = den + n0[i] * e0 + n1[i] * e1 + n2[i] * e2;
            const float w   = ds[i] * t * __builtin_amdgcn_rcpf(den + 1e-18f);
            vd[i] = fminf(fmaxf(w, 0.01f), 10.0f);
        }
    } else if (sy >= 0 && sy < IH) {
        const float fy = (float)y;
#pragma unroll
        for (int i = 0; i < 4; ++i) {
            const int sx = x0 + i + ox;
            if (sx >= 0 && sx < IW) {
                const int sp = sy * IW + sx;
                const float n0 = nr[sp];
                const float n1 = nr[IHW + sp];
                const float n2 = nr[2 * IHW + sp];
                const float fx = (float)(x0 + i);
                const float r0 = k00 * fx + k01 * fy + k02;
                const float r1 = k10 * fx + k11 * fy + k12;
                const float r2 = k20 * fx + k21 * fy + k22;
                const float den = n0 * r0 + n1 * r1 + n2 * r2;
                const float t   = den + n0 * e0 + n1 * e1 + n2 * e2;
                const float w   = dp[sp] * t * __builtin_amdgcn_rcpf(den + 1e-18f);
                vd[i] = fminf(fmaxf(w, 0.01f), 10.0f);
                vc[i] = cfp[sp];
                v0[i] = rg[sp];
                v1[i] = rg[IHW + sp];
                v2[i] = rg[2 * IHW + sp];
            } else {
                vd[i] = dp[p0 + i];   // boundary pass-through
                vc[i] = 0.0f; v0[i] = 0.0f; v1[i] = 0.0f; v2[i] = 0.0f;
            }
        }
    } else {
#pragma unroll
        for (int i = 0; i < 4; ++i) {
            const int sx = x0 + i + ox;
            // ld-d2 quirk: bottom boundary passes depth[y, x-o] through
            if (k == 7 && sy >= IH && sx >= 0) vd[i] = dp[p0 + i + ox];
            else                               vd[i] = dp[p0 + i];
        }
        vc = (f32x4)0.0f; v0 = (f32x4)0.0f; v1 = (f32x4)0.0f; v2 = (f32x4)0.0f;
    }

    float* outc = out + (((size_t)bi * 24 + c) * 5) * IHW + p0;
    __builtin_nontemporal_store(vd, reinterpret_cast<f32x4*>(outc));
    __builtin_nontemporal_store(vc, reinterpret_cast<f32x4*>(outc + IHW));
    __builtin_nontemporal_store(v0, reinterpret_cast<f32x4*>(outc + 2 * IHW));
    __builtin_nontemporal_store(v1, reinterpret_cast<f32x4*>(outc + 3 * IHW));
    __builtin_nontemporal_store(v2, reinterpret_cast<f32x4*>(outc + 4 * IHW));
}

extern "C" void kernel_launch(void* const* d_in, const int* in_sizes, int n_in,
                              void* d_out, int out_size, void* d_ws, size_t ws_size,
                              hipStream_t stream) {
    const float* depth  = (const float*)d_in[0];
    const float* normal = (const float*)d_in[1];
    const float* rgb    = (const float*)d_in[2];
    const float* conf   = (const float*)d_in[3];
    const float* Kinv   = (const float*)d_in[4];
    float* out = (float*)d_out;

    const int B = in_sizes[0] / IHW;
    dim3 grid(IHW / (256 * 4), 24, B);   // (300, 24, B) = 14400 blocks
    dim3 block(256, 1, 1);

    hipLaunchKernelGGL(prop_kernel, grid, block, 0, stream,
                       depth, normal, rgb, conf, Kinv, out);
}

// Round 12
// 65.724 us; speedup vs baseline: 1.6511x; 1.2707x over previous
//
#include <hip/hip_runtime.h>

static constexpr int IH = 480;
static constexpr int IW = 640;
static constexpr int IHW = IH * IW;
static constexpr int NCH = IHW / 256;   // 1200 pixel-chunks of 256 px

// 8 (axis, dir) combos in reference order: ud d1/d2, lr d1/d2, lu d1/d2, ld d1/d2
__device__ __constant__ const int c_oy[8] = { -1, +1,  0,  0, -1, +1, -1, +1 };
__device__ __constant__ const int c_ox[8] = {  0,  0, -1, +1, -1, +1, +1, -1 };

__global__ __launch_bounds__(256) void prop_kernel(
    const float* __restrict__ depth,
    const float* __restrict__ normal,
    const float* __restrict__ rgb,
    const float* __restrict__ conf,
    const float* __restrict__ Kinv,
    float* __restrict__ out,
    int nwg)
{
    // --- XCD-locality swizzle (bijective, m204 form) ---
    // HW round-robins linear block id over 8 XCDs. Remap so each XCD owns a
    // CONTIGUOUS range of work items, with combo the fastest-varying field:
    // all 24 combos of a pixel-chunk run back-to-back on ONE XCD, and each
    // XCD's chunk range (1/4 image at B=2) fits its 4 MiB L2.
    const int l  = blockIdx.x;
    const int xc = l & 7;               // XCD this block lands on
    const int j  = l >> 3;              // per-XCD sequence number
    const int q  = nwg >> 3, r8 = nwg & 7;
    const int w  = xc * q + (xc < r8 ? xc : r8) + j;   // contiguous work index

    const int c   = w % 24;             // combo (fastest)
    const int wt  = w / 24;
    const int t   = wt % NCH;           // pixel-chunk
    const int bi  = wt / NCH;           // batch

    const int oi = c >> 3;
    const int k  = c & 7;
    const int o  = 2 * oi + 1;          // 1, 3, 5
    const int oy = c_oy[k] * o;
    const int ox = c_ox[k] * o;

    const int p  = t * 256 + threadIdx.x;   // pixel, 1:1
    const int y  = p / IW;
    const int x  = p - y * IW;
    const int sy = y + oy;
    const int sx = x + ox;
    const bool inb = (sx >= 0) & (sx < IW) & (sy >= 0) & (sy < IH);

    const float* dp  = depth  + (size_t)bi * IHW;
    const float* cfp = conf   + (size_t)bi * IHW;
    const float* nr  = normal + (size_t)bi * 3 * IHW;
    const float* rg  = rgb    + (size_t)bi * 3 * IHW;

    float od, oc, og0, og1, og2;
    if (inb) {
        const float* Ki = Kinv + bi * 9;
        const float k00 = Ki[0], k01 = Ki[1], k02 = Ki[2];
        const float k10 = Ki[3], k11 = Ki[4], k12 = Ki[5];
        const float k20 = Ki[6], k21 = Ki[7], k22 = Ki[8];
        const float fx = (float)x, fy = (float)y;
        const float r0 = k00 * fx + k01 * fy + k02;     // ray at dest pixel
        const float r1 = k10 * fx + k11 * fy + k12;
        const float r2 = k20 * fx + k21 * fy + k22;
        const float fox = (float)ox, foy = (float)oy;
        const float e0 = fox * k00 + foy * k01;         // K_inv * (ox,oy,0)
        const float e1 = fox * k10 + foy * k11;
        const float e2 = fox * k20 + foy * k21;

        const int sp = sy * IW + sx;
        const float n0 = nr[sp];
        const float n1 = nr[IHW + sp];
        const float n2 = nr[2 * IHW + sp];
        const float den = n0 * r0 + n1 * r1 + n2 * r2;  // n_s . ray_dest
        const float tt  = den + n0 * e0 + n1 * e1 + n2 * e2;
        const float ww  = dp[sp] * tt * __builtin_amdgcn_rcpf(den + 1e-18f);
        od  = fminf(fmaxf(ww, 0.01f), 10.0f);
        oc  = cfp[sp];
        og0 = rg[sp];
        og1 = rg[IHW + sp];
        og2 = rg[2 * IHW + sp];
    } else {
        // boundary pass-through; ld-d2 (k==7) bottom edge uses depth[y, x-o]
        if (k == 7 && sy >= IH && sx >= 0) od = dp[y * IW + sx];
        else                               od = dp[p];
        oc = 0.0f; og0 = 0.0f; og1 = 0.0f; og2 = 0.0f;
    }

    float* ob = out + (((size_t)bi * 24 + c) * 5) * IHW + p;
    __builtin_nontemporal_store(od,  ob);
    __builtin_nontemporal_store(oc,  ob + IHW);
    __builtin_nontemporal_store(og0, ob + 2 * IHW);
    __builtin_nontemporal_store(og1, ob + 3 * IHW);
    __builtin_nontemporal_store(og2, ob + 4 * IHW);
}

extern "C" void kernel_launch(void* const* d_in, const int* in_sizes, int n_in,
                              void* d_out, int out_size, void* d_ws, size_t ws_size,
                              hipStream_t stream) {
    const float* depth  = (const float*)d_in[0];
    const float* normal = (const float*)d_in[1];
    const float* rgb    = (const float*)d_in[2];
    const float* conf   = (const float*)d_in[3];
    const float* Kinv   = (const float*)d_in[4];
    float* out = (float*)d_out;

    const int B = in_sizes[0] / IHW;
    const int nwg = NCH * 24 * B;       // 57600 at B=2
    dim3 grid(nwg, 1, 1);
    dim3 block(256, 1, 1);

    hipLaunchKernelGGL(prop_kernel, grid, block, 0, stream,
                       depth, normal, rgb, conf, Kinv, out, nwg);
}